// Round 1
// baseline (67.450 us; speedup 1.0000x reference)
//
#include <hip/hip_runtime.h>
#include <hip/hip_bf16.h>

#define G 32
#define NNBR 16
#define ATOM_TYPE 6

// Block: 256 threads. Grid: (B*A, 8). Each block handles one (b,a) pair and
// a slab of 4 i-planes (4*32*32 = 4096 voxels -> 16 voxels/thread).
__global__ __launch_bounds__(256) void voxel_kernel(
    const float* __restrict__ dv,     // (B=4, A=32, N=16, 3)
    const int*   __restrict__ an,     // (A=32, N=16) int32
    const float* __restrict__ sigma,  // (1,)
    float*       __restrict__ out)    // (B, A, G, G, G)
{
    const int ba    = blockIdx.x;        // 0..127 : b*32 + a
    const int a     = ba & 31;
    const int islab = blockIdx.y;        // 0..7 : i in [islab*4, islab*4+4)
    const int tid   = threadIdx.x;

    __shared__ float sEx[NNBR][G];
    __shared__ float sEy[NNBR][G];
    __shared__ float sEz[NNBR][G];
    __shared__ int   sIdx[NNBR];
    __shared__ int   sM;

    // Compact the list of neighbors with atomic_number == ATOM_TYPE.
    if (tid == 0) {
        int m = 0;
        #pragma unroll
        for (int n = 0; n < NNBR; ++n) {
            if (an[a * NNBR + n] == ATOM_TYPE) sIdx[m++] = n;
        }
        sM = m;
    }
    __syncthreads();

    const int   M     = sM;
    const float s     = sigma[0];
    const float coeff = -0.5f / (s * s);
    const float step  = 8.0f / 31.0f;    // linspace(-4, 4, 32) spacing

    // Fill separable exp tables for the M masked neighbors.
    for (int idx = tid; idx < M * G; idx += 256) {
        const int m = idx >> 5;
        const int i = idx & 31;
        const int n = sIdx[m];
        const float* d = dv + ((size_t)ba * NNBR + n) * 3;
        const float t  = -4.0f + (float)i * step;
        const float dx = t - d[0];
        const float dy = t - d[1];
        const float dz = t - d[2];
        sEx[m][i] = __expf(coeff * dx * dx);
        sEy[m][i] = __expf(coeff * dy * dy);
        sEz[m][i] = __expf(coeff * dz * dz);
    }
    __syncthreads();

    // Each thread has fixed k = tid & 31 across its 16 voxels: hoist Ez.
    const int k = tid & 31;
    float ez[NNBR];
    for (int m = 0; m < M; ++m) ez[m] = sEz[m][k];

    float* outp = out + (size_t)ba * (G * G * G) + (size_t)islab * 4096;

    #pragma unroll
    for (int sstep = 0; sstep < 16; ++sstep) {
        const int vl = tid + (sstep << 8);       // local voxel 0..4095
        const int j  = (vl >> 5) & 31;
        const int il = vl >> 10;                 // 0..3 within slab
        const int i  = islab * 4 + il;
        float acc = 0.0f;
        for (int m = 0; m < M; ++m) {
            acc += sEx[m][i] * (sEy[m][j] * ez[m]);
        }
        outp[vl] = acc;
    }
}

extern "C" void kernel_launch(void* const* d_in, const int* in_sizes, int n_in,
                              void* d_out, int out_size, void* d_ws, size_t ws_size,
                              hipStream_t stream) {
    const float* dv    = (const float*)d_in[0];   // (4,32,16,3)
    const int*   an    = (const int*)d_in[1];     // (32,16)
    const float* sigma = (const float*)d_in[2];   // (1,)
    float*       out   = (float*)d_out;           // (4,32,32,32,32)

    dim3 grid(4 * 32, 8);
    dim3 block(256);
    voxel_kernel<<<grid, block, 0, stream>>>(dv, an, sigma, out);
}

// Round 2
// 63.795 us; speedup vs baseline: 1.0573x; 1.0573x over previous
//
#include <hip/hip_runtime.h>
#include <hip/hip_bf16.h>

#define G 32
#define NNBR 16
#define ATOM_TYPE 6

// Block: 256 threads. Grid: (B*A, 8). Each block handles one (b,a) pair and
// a slab of 4 i-planes (4*32*32 = 4096 voxels = 1024 float4s -> 4 float4/thread).
// Thread mapping: j = tid>>3, k0 = (tid&7)*4 fixed; i = islab*4 + s, s=0..3.
__global__ __launch_bounds__(256) void voxel_kernel(
    const float* __restrict__ dv,     // (B=4, A=32, N=16, 3)
    const int*   __restrict__ an,     // (A=32, N=16) int32
    const float* __restrict__ sigma,  // (1,)
    float*       __restrict__ out)    // (B, A, G, G, G)
{
    const int ba    = blockIdx.x;        // b*32 + a
    const int a     = ba & 31;
    const int islab = blockIdx.y;        // 0..7
    const int tid   = threadIdx.x;

    __shared__ __align__(16) float sEx[NNBR][G];
    __shared__ __align__(16) float sEy[NNBR][G];
    __shared__ __align__(16) float sEz[NNBR][G];
    __shared__ float sDv[NNBR * 3];
    __shared__ int   sIdx[NNBR];
    __shared__ int   sM;

    // Prefetch distance vectors (48 floats) — issues in parallel with an load.
    if (tid < NNBR * 3) sDv[tid] = dv[(size_t)ba * (NNBR * 3) + tid];

    // Parallel mask compaction: one load per neighbor + ballot prefix-sum.
    int flag = 0;
    if (tid < NNBR) flag = (an[a * NNBR + tid] == ATOM_TYPE) ? 1 : 0;
    unsigned long long mask = __ballot(flag);   // meaningful in wave 0 only
    if (flag) {
        int pos = __popcll(mask & ((1ull << tid) - 1ull));
        sIdx[pos] = tid;
    }
    if (tid == 0) sM = (int)__popcll(mask);
    __syncthreads();

    const int   M     = sM;
    const float s     = sigma[0];
    const float coeff = -0.5f / (s * s);
    const float step  = 8.0f / 31.0f;    // linspace(-4,4,32) spacing

    // Fill separable exp tables for the M masked neighbors (M*32 <= 512 items).
    for (int idx = tid; idx < M * G; idx += 256) {
        const int m = idx >> 5;
        const int i = idx & 31;
        const int n = sIdx[m];
        const float t  = -4.0f + (float)i * step;
        const float dx = t - sDv[3 * n + 0];
        const float dy = t - sDv[3 * n + 1];
        const float dz = t - sDv[3 * n + 2];
        sEx[m][i] = __expf(coeff * dx * dx);
        sEy[m][i] = __expf(coeff * dy * dy);
        sEz[m][i] = __expf(coeff * dz * dz);
    }
    __syncthreads();

    const int j  = tid >> 3;            // 0..31
    const int k0 = (tid & 7) * 4;       // 0,4,...,28
    const int i0 = islab * 4;

    float4 acc0 = {0.f, 0.f, 0.f, 0.f};
    float4 acc1 = acc0, acc2 = acc0, acc3 = acc0;

    for (int m = 0; m < M; ++m) {
        const float  ey = sEy[m][j];
        const float4 ez = *(const float4*)&sEz[m][k0];
        const float4 ex = *(const float4*)&sEx[m][i0];
        const float p0 = ex.x * ey, p1 = ex.y * ey, p2 = ex.z * ey, p3 = ex.w * ey;
        acc0.x += p0 * ez.x; acc0.y += p0 * ez.y; acc0.z += p0 * ez.z; acc0.w += p0 * ez.w;
        acc1.x += p1 * ez.x; acc1.y += p1 * ez.y; acc1.z += p1 * ez.z; acc1.w += p1 * ez.w;
        acc2.x += p2 * ez.x; acc2.y += p2 * ez.y; acc2.z += p2 * ez.z; acc2.w += p2 * ez.w;
        acc3.x += p3 * ez.x; acc3.y += p3 * ez.y; acc3.z += p3 * ez.z; acc3.w += p3 * ez.w;
    }

    // Coalesced float4 stores: instr s -> lanes cover 4 KB dense.
    float4* out4 = (float4*)(out + (size_t)ba * (G * G * G) + (size_t)islab * 4096);
    out4[0 * 256 + tid] = acc0;
    out4[1 * 256 + tid] = acc1;
    out4[2 * 256 + tid] = acc2;
    out4[3 * 256 + tid] = acc3;
}

extern "C" void kernel_launch(void* const* d_in, const int* in_sizes, int n_in,
                              void* d_out, int out_size, void* d_ws, size_t ws_size,
                              hipStream_t stream) {
    const float* dv    = (const float*)d_in[0];   // (4,32,16,3)
    const int*   an    = (const int*)d_in[1];     // (32,16)
    const float* sigma = (const float*)d_in[2];   // (1,)
    float*       out   = (float*)d_out;           // (4,32,32,32,32)

    dim3 grid(4 * 32, 8);
    dim3 block(256);
    voxel_kernel<<<grid, block, 0, stream>>>(dv, an, sigma, out);
}